// Round 1
// baseline (2568.303 us; speedup 1.0000x reference)
//
#include <hip/hip_runtime.h>
#include <math.h>

#define NT 384   // turns
#define TL 384   // per-turn seq len
#define HD 768   // hidden
#define DD 128   // qk proj dim

// ---------------------------------------------------------------------------
// K1: q = (x @ Wq + bq) * (1/sqrt(D));  k = x @ Wk + bk
// block: 256 threads, 16 rows of x staged in LDS. Each 128-thread group owns
// 8 rows; thread d computes columns for q and k. Wq/Wk reads coalesced, L2-hot.
// ---------------------------------------------------------------------------
__global__ __launch_bounds__(256) void k_proj(
    const float* __restrict__ x, const float* __restrict__ Wq, const float* __restrict__ bq,
    const float* __restrict__ Wk, const float* __restrict__ bk,
    float* __restrict__ q, float* __restrict__ k)
{
    __shared__ float xs[16 * HD];
    const int tid = threadIdx.x;
    const size_t row0 = (size_t)blockIdx.x * 16;
    {
        const float4* src = (const float4*)(x + row0 * HD);
        float4* dst = (float4*)xs;
        #pragma unroll
        for (int m = 0; m < 12; ++m) dst[m * 256 + tid] = src[m * 256 + tid];
    }
    __syncthreads();
    const int d = tid & 127;
    const int g = tid >> 7;  // 0..1 -> rows g*8 .. g*8+7
    float accq[8], acck[8];
    #pragma unroll
    for (int r = 0; r < 8; ++r) { accq[r] = 0.f; acck[r] = 0.f; }
    for (int h = 0; h < HD; h += 4) {
        const float wq0 = Wq[(h + 0) * DD + d];
        const float wq1 = Wq[(h + 1) * DD + d];
        const float wq2 = Wq[(h + 2) * DD + d];
        const float wq3 = Wq[(h + 3) * DD + d];
        const float wk0 = Wk[(h + 0) * DD + d];
        const float wk1 = Wk[(h + 1) * DD + d];
        const float wk2 = Wk[(h + 2) * DD + d];
        const float wk3 = Wk[(h + 3) * DD + d];
        #pragma unroll
        for (int r = 0; r < 8; ++r) {
            const float4 xv = *(const float4*)&xs[(g * 8 + r) * HD + h];
            accq[r] = fmaf(xv.x, wq0, accq[r]);
            accq[r] = fmaf(xv.y, wq1, accq[r]);
            accq[r] = fmaf(xv.z, wq2, accq[r]);
            accq[r] = fmaf(xv.w, wq3, accq[r]);
            acck[r] = fmaf(xv.x, wk0, acck[r]);
            acck[r] = fmaf(xv.y, wk1, acck[r]);
            acck[r] = fmaf(xv.z, wk2, acck[r]);
            acck[r] = fmaf(xv.w, wk3, acck[r]);
        }
    }
    const float bqv = bq[d], bkv = bk[d];
    const float scale = 0.08838834764831845f;  // 1/sqrt(128)
    #pragma unroll
    for (int r = 0; r < 8; ++r) {
        const size_t row = row0 + g * 8 + r;
        q[row * DD + d] = (accq[r] + bqv) * scale;   // fold 1/sqrt(D) into q
        k[row * DD + d] = acck[r] + bkv;
    }
}

// ---------------------------------------------------------------------------
// K2: for block (t, i-tile of 32): loop over j in chunks of 64.
//   s(i,j,t) = q[i,t,:].k[j,t,:]  (scale already folded into q)
//   w = (j<=i) ? exp(s) : 0
//   accumulate out_unnorm[i,t,:] += w * x[j,t,:]  (96 fp32 accs/thread)
//   accumulate lpart[i][t] = sum_j w              (for the joint softmax denom)
// No max subtraction: s ~ N(0,1), max ~6 over the whole tensor -> exp safe.
// LDS k/q tiles are XOR-swizzled at float4 granularity to avoid the
// stride-128-row bank conflicts (32-way otherwise).
// ---------------------------------------------------------------------------
__global__ __launch_bounds__(256) void k_attn(
    const float* __restrict__ q, const float* __restrict__ k, const float* __restrict__ x,
    float* __restrict__ out, float* __restrict__ lpart)
{
    const int t  = blockIdx.x;
    const int i0 = blockIdx.y * 32;
    const int jmax = i0 + 32;
    const int tid = threadIdx.x;
    __shared__ float qs[32 * DD];
    __shared__ float ks[64 * DD];
    __shared__ float wb[64 * 36];    // [jj][ii] transposed, padded to 36
    float4* qs4 = (float4*)qs;
    float4* ks4 = (float4*)ks;

    // stage q tile (32 rows x 128), swizzled
    #pragma unroll
    for (int m = 0; m < 4; ++m) {
        const int flat = m * 256 + tid;
        const int ii = flat >> 5, d4 = flat & 31;
        const float4 v = *(const float4*)&q[(((size_t)(i0 + ii)) * TL + t) * DD + d4 * 4];
        qs4[ii * 32 + (d4 ^ ((ii >> 1) & 7))] = v;
    }

    float acc[32][3];
    #pragma unroll
    for (int ii = 0; ii < 32; ++ii) { acc[ii][0] = 0.f; acc[ii][1] = 0.f; acc[ii][2] = 0.f; }
    float lsum0 = 0.f, lsum1 = 0.f;
    const int ii0 = (tid >> 4) << 1;       // 0,2,..,30
    const int jj0 = (tid & 15) << 2;       // 0,4,..,60
    const int xq  = (ii0 >> 1) & 7;
    const int xk  = (tid & 15) & 7;        // == ((jj0+r)>>2)&7 for r in 0..3

    for (int j0 = 0; j0 < jmax; j0 += 64) {
        __syncthreads();  // wb/ks reuse safety across chunks
        // stage k tile (64 rows x 128), zero-padded past jmax, swizzled
        #pragma unroll
        for (int m = 0; m < 8; ++m) {
            const int flat = m * 256 + tid;
            const int jj = flat >> 5, d4 = flat & 31;
            const int j = j0 + jj;
            float4 v = make_float4(0.f, 0.f, 0.f, 0.f);
            if (j < jmax) v = *(const float4*)&k[(((size_t)j) * TL + t) * DD + d4 * 4];
            ks4[jj * 32 + (d4 ^ ((jj >> 2) & 7))] = v;
        }
        __syncthreads();

        // compute s for micro-tile 2(ii) x 4(jj)
        float sA[4], sB[4];
        #pragma unroll
        for (int r = 0; r < 4; ++r) { sA[r] = 0.f; sB[r] = 0.f; }
        for (int d4 = 0; d4 < 32; ++d4) {
            const float4 qa = qs4[ ii0      * 32 + (d4 ^ xq)];
            const float4 qb = qs4[(ii0 + 1) * 32 + (d4 ^ xq)];
            #pragma unroll
            for (int r = 0; r < 4; ++r) {
                const float4 kv = ks4[(jj0 + r) * 32 + (d4 ^ xk)];
                sA[r] = fmaf(qa.x, kv.x, sA[r]);
                sA[r] = fmaf(qa.y, kv.y, sA[r]);
                sA[r] = fmaf(qa.z, kv.z, sA[r]);
                sA[r] = fmaf(qa.w, kv.w, sA[r]);
                sB[r] = fmaf(qb.x, kv.x, sB[r]);
                sB[r] = fmaf(qb.y, kv.y, sB[r]);
                sB[r] = fmaf(qb.z, kv.z, sB[r]);
                sB[r] = fmaf(qb.w, kv.w, sB[r]);
            }
        }
        // mask + exp + store transposed + row-sum partials
        float ps0 = 0.f, ps1 = 0.f;
        #pragma unroll
        for (int r = 0; r < 4; ++r) {
            const int j = j0 + jj0 + r;
            const float w0 = (j <= i0 + ii0    ) ? __expf(sA[r]) : 0.f;
            const float w1 = (j <= i0 + ii0 + 1) ? __expf(sB[r]) : 0.f;
            wb[(jj0 + r) * 36 + ii0    ] = w0;
            wb[(jj0 + r) * 36 + ii0 + 1] = w1;
            ps0 += w0; ps1 += w1;
        }
        #pragma unroll
        for (int off = 1; off < 16; off <<= 1) {
            ps0 += __shfl_xor(ps0, off);
            ps1 += __shfl_xor(ps1, off);
        }
        lsum0 += ps0; lsum1 += ps1;
        __syncthreads();

        // accumulate out_unnorm
        const int jend = min(64, jmax - j0);
        for (int jj = 0; jj < jend; ++jj) {
            const size_t xoff = (((size_t)(j0 + jj)) * TL + t) * HD + tid;
            const float xv0 = x[xoff];
            const float xv1 = x[xoff + 256];
            const float xv2 = x[xoff + 512];
            const float4* wrow = (const float4*)&wb[jj * 36];
            #pragma unroll
            for (int c8 = 0; c8 < 8; ++c8) {
                const float4 w4 = wrow[c8];
                acc[c8 * 4 + 0][0] = fmaf(w4.x, xv0, acc[c8 * 4 + 0][0]);
                acc[c8 * 4 + 0][1] = fmaf(w4.x, xv1, acc[c8 * 4 + 0][1]);
                acc[c8 * 4 + 0][2] = fmaf(w4.x, xv2, acc[c8 * 4 + 0][2]);
                acc[c8 * 4 + 1][0] = fmaf(w4.y, xv0, acc[c8 * 4 + 1][0]);
                acc[c8 * 4 + 1][1] = fmaf(w4.y, xv1, acc[c8 * 4 + 1][1]);
                acc[c8 * 4 + 1][2] = fmaf(w4.y, xv2, acc[c8 * 4 + 1][2]);
                acc[c8 * 4 + 2][0] = fmaf(w4.z, xv0, acc[c8 * 4 + 2][0]);
                acc[c8 * 4 + 2][1] = fmaf(w4.z, xv1, acc[c8 * 4 + 2][1]);
                acc[c8 * 4 + 2][2] = fmaf(w4.z, xv2, acc[c8 * 4 + 2][2]);
                acc[c8 * 4 + 3][0] = fmaf(w4.w, xv0, acc[c8 * 4 + 3][0]);
                acc[c8 * 4 + 3][1] = fmaf(w4.w, xv1, acc[c8 * 4 + 3][1]);
                acc[c8 * 4 + 3][2] = fmaf(w4.w, xv2, acc[c8 * 4 + 3][2]);
            }
        }
    }

    // write unnormalized out
    #pragma unroll
    for (int ii = 0; ii < 32; ++ii) {
        const size_t ooff = (((size_t)(i0 + ii)) * TL + t) * HD + tid;
        out[ooff]       = acc[ii][0];
        out[ooff + 256] = acc[ii][1];
        out[ooff + 512] = acc[ii][2];
    }
    if ((tid & 15) == 0) {
        lpart[((size_t)(i0 + ii0    )) * TL + t] = lsum0;
        lpart[((size_t)(i0 + ii0 + 1)) * TL + t] = lsum1;
    }
}

// ---------------------------------------------------------------------------
// K3: linv[i] = 1 / sum_t lpart[i][t]
// ---------------------------------------------------------------------------
__global__ __launch_bounds__(256) void k_lred(const float* __restrict__ lpart,
                                              float* __restrict__ linv)
{
    const int i = blockIdx.x;
    const int tid = threadIdx.x;
    float s = 0.f;
    for (int t = tid; t < TL; t += 256) s += lpart[(size_t)i * TL + t];
    #pragma unroll
    for (int off = 32; off >= 1; off >>= 1) s += __shfl_down(s, off);
    __shared__ float red[4];
    if ((tid & 63) == 0) red[tid >> 6] = s;
    __syncthreads();
    if (tid == 0) linv[i] = 1.f / (red[0] + red[1] + red[2] + red[3]);
}

// ---------------------------------------------------------------------------
// K4: out[i] *= linv[i] for i>=1; out[0] = x[0] (passthrough)
// ---------------------------------------------------------------------------
__global__ __launch_bounds__(256) void k_norm(
    const float* __restrict__ x, const float* __restrict__ linv, float* __restrict__ out)
{
    const int i = blockIdx.y;
    const size_t base = (size_t)i * (TL * HD / 4) + (size_t)blockIdx.x * 256 + threadIdx.x;
    float4* o4 = (float4*)out;
    if (i == 0) {
        o4[base] = ((const float4*)x)[base];
    } else {
        const float s = linv[i];
        float4 v = o4[base];
        v.x *= s; v.y *= s; v.z *= s; v.w *= s;
        o4[base] = v;
    }
}

extern "C" void kernel_launch(void* const* d_in, const int* in_sizes, int n_in,
                              void* d_out, int out_size, void* d_ws, size_t ws_size,
                              hipStream_t stream)
{
    const float* x  = (const float*)d_in[0];
    const float* Wq = (const float*)d_in[1];
    const float* bq = (const float*)d_in[2];
    const float* Wk = (const float*)d_in[3];
    const float* bk = (const float*)d_in[4];
    float* out = (float*)d_out;

    float* q     = (float*)d_ws;                       // NT*TL*DD floats
    float* k     = q + (size_t)NT * TL * DD;           // NT*TL*DD floats
    float* lpart = k + (size_t)NT * TL * DD;           // NT*TL floats
    float* linv  = lpart + (size_t)NT * TL;            // NT floats

    k_proj<<<dim3(NT * TL / 16), 256, 0, stream>>>(x, Wq, bq, Wk, bk, q, k);
    k_attn<<<dim3(TL, NT / 32), 256, 0, stream>>>(q, k, x, out, lpart);
    k_lred<<<dim3(NT), 256, 0, stream>>>(lpart, linv);
    k_norm<<<dim3(TL * HD / 4 / 256, NT), 256, 0, stream>>>(x, linv, out);
}

// Round 2
// 857.184 us; speedup vs baseline: 2.9962x; 2.9962x over previous
//
#include <hip/hip_runtime.h>
#include <hip/hip_bf16.h>
#include <math.h>

#define NT 384   // turns
#define TL 384   // per-turn seq len
#define HD 768   // hidden
#define DD 128   // qk proj dim

typedef __attribute__((ext_vector_type(8))) short bf16x8;
typedef __attribute__((ext_vector_type(8))) unsigned short u16x8;
typedef __attribute__((ext_vector_type(4))) float f32x4;

__device__ __forceinline__ unsigned short f2b(float f) {
    union { float f; unsigned int u; } v; v.f = f;
    unsigned int r = v.u + 0x7FFFu + ((v.u >> 16) & 1u);   // RNE
    return (unsigned short)(r >> 16);
}

// ---------------------------------------------------------------------------
// kw_prep: Wt[n][k] = bf16(n<128 ? Wq[k][n] : Wk[k][n-128]); [256][768]
// ---------------------------------------------------------------------------
__global__ __launch_bounds__(256) void kw_prep(
    const float* __restrict__ Wq, const float* __restrict__ Wk,
    unsigned short* __restrict__ Wt)
{
    const int idx = blockIdx.x * 256 + threadIdx.x;     // 0 .. 196607
    const int k = idx >> 8, n = idx & 255;
    const float v = (n < DD) ? Wq[(size_t)k * DD + n] : Wk[(size_t)k * DD + (n - DD)];
    Wt[(size_t)n * HD + k] = f2b(v);
}

// ---------------------------------------------------------------------------
// k_proj: MFMA GEMM  C[147456][256] = x[147456][768] @ (Wq|Wk)[768][256]
// block: 64 rows, 256 threads (4 waves), wave w owns cols w*64..+64.
// A (x) staged fp32->bf16 in XOR-swizzled LDS; B frags direct from Wt (L2).
// q gets (acc+bq)*1/sqrt(D); k gets acc+bk. bf16 out, layout [i*T+t][d].
// ---------------------------------------------------------------------------
__global__ __launch_bounds__(256, 2) void k_proj(
    const float* __restrict__ x, const unsigned short* __restrict__ Wt,
    const float* __restrict__ bq, const float* __restrict__ bk,
    unsigned short* __restrict__ qg, unsigned short* __restrict__ kg)
{
    __shared__ unsigned short As[64 * 64];   // [m][k] bf16, 16B-chunk XOR swizzle
    const int tid = threadIdx.x;
    const int lane = tid & 63;
    const int w = tid >> 6;
    const int row0 = blockIdx.x * 64;
    const int n0w = w * 64;
    const int lr = lane & 15;
    const int lg = lane >> 4;

    f32x4 acc[4][4];
    #pragma unroll
    for (int m = 0; m < 4; ++m)
        #pragma unroll
        for (int n = 0; n < 4; ++n) acc[m][n] = (f32x4){0.f, 0.f, 0.f, 0.f};

    const int sm = tid >> 2;           // staging row 0..63
    const int sc0 = (tid & 3) * 2;     // staging 16B-chunk pair

    for (int k0 = 0; k0 < HD; k0 += 64) {
        __syncthreads();
        {   // stage A tile [64 m][64 k] as bf16, swizzled
            const float* xp = x + (size_t)(row0 + sm) * HD + k0 + (tid & 3) * 16;
            u16x8 v0, v1;
            #pragma unroll
            for (int u4 = 0; u4 < 2; ++u4) {
                float4 f = *(const float4*)(xp + u4 * 4);
                v0[u4*4+0] = f2b(f.x); v0[u4*4+1] = f2b(f.y);
                v0[u4*4+2] = f2b(f.z); v0[u4*4+3] = f2b(f.w);
            }
            #pragma unroll
            for (int u4 = 0; u4 < 2; ++u4) {
                float4 f = *(const float4*)(xp + 8 + u4 * 4);
                v1[u4*4+0] = f2b(f.x); v1[u4*4+1] = f2b(f.y);
                v1[u4*4+2] = f2b(f.z); v1[u4*4+3] = f2b(f.w);
            }
            *(u16x8*)&As[sm * 64 + ((sc0     ^ (sm & 7)) * 8)] = v0;
            *(u16x8*)&As[sm * 64 + (((sc0+1) ^ (sm & 7)) * 8)] = v1;
        }
        __syncthreads();
        #pragma unroll
        for (int kk = 0; kk < 2; ++kk) {
            bf16x8 a[4], b[4];
            #pragma unroll
            for (int m = 0; m < 4; ++m) {
                const int mi = m * 16 + lr;
                const int phys = (lg + kk * 4) ^ (mi & 7);
                a[m] = *(const bf16x8*)&As[mi * 64 + phys * 8];
            }
            #pragma unroll
            for (int n = 0; n < 4; ++n) {
                const int ncol = n0w + n * 16 + lr;
                b[n] = *(const bf16x8*)(Wt + (size_t)ncol * HD + k0 + kk * 32 + lg * 8);
            }
            #pragma unroll
            for (int m = 0; m < 4; ++m)
                #pragma unroll
                for (int n = 0; n < 4; ++n)
                    acc[m][n] = __builtin_amdgcn_mfma_f32_16x16x32_bf16(a[m], b[n], acc[m][n], 0, 0, 0);
        }
    }
    const float scale = 0.08838834764831845f;   // 1/sqrt(128), folded into q
    #pragma unroll
    for (int n = 0; n < 4; ++n) {
        const int ncol = n0w + n * 16 + lr;
        const bool isq = ncol < DD;
        const int d = isq ? ncol : ncol - DD;
        const float bias = isq ? bq[d] : bk[d];
        unsigned short* dst = isq ? qg : kg;
        #pragma unroll
        for (int m = 0; m < 4; ++m)
            #pragma unroll
            for (int r = 0; r < 4; ++r) {
                const int row = row0 + m * 16 + lg * 4 + r;
                float v = acc[m][n][r] + bias;
                if (isq) v *= scale;
                dst[(size_t)row * DD + d] = f2b(v);
            }
    }
}

// ---------------------------------------------------------------------------
// k_stats: per (i-tile 32, t): S = QK^T (MFMA), w = mask ? exp(s) : 0,
// lpart[i][t] = sum_j w. Waves split j (16 cols each) per 64-chunk.
// ---------------------------------------------------------------------------
__global__ __launch_bounds__(256, 2) void k_stats(
    const unsigned short* __restrict__ qg, const unsigned short* __restrict__ kg,
    float* __restrict__ lpart)
{
    __shared__ float red[4][32];
    const int tid = threadIdx.x, lane = tid & 63, w = tid >> 6;
    const int lr = lane & 15, lg = lane >> 4;
    const int bid = blockIdx.x;
    const int lid = (bid & 7) * (4608 / 8) + (bid >> 3);   // XCD-chunk swizzle
    const int it = lid % 12, t = lid / 12;
    const int i0 = it * 32;

    bf16x8 aq[2][4];
    #pragma unroll
    for (int m = 0; m < 2; ++m) {
        const unsigned short* qp = qg + ((size_t)(i0 + m * 16 + lr) * TL + t) * DD + lg * 8;
        #pragma unroll
        for (int kk = 0; kk < 4; ++kk) aq[m][kk] = *(const bf16x8*)(qp + kk * 32);
    }
    float psum[2][4];
    #pragma unroll
    for (int m = 0; m < 2; ++m)
        #pragma unroll
        for (int r = 0; r < 4; ++r) psum[m][r] = 0.f;

    const int jmax = i0 + 32;
    const int nch = (jmax + 63) >> 6;
    for (int c = 0; c < nch; ++c) {
        const int j0 = c * 64;
        f32x4 s[2] = { (f32x4){0,0,0,0}, (f32x4){0,0,0,0} };
        const unsigned short* kp = kg + ((size_t)(j0 + w * 16 + lr) * TL + t) * DD + lg * 8;
        #pragma unroll
        for (int kk = 0; kk < 4; ++kk) {
            const bf16x8 bk8 = *(const bf16x8*)(kp + kk * 32);
            s[0] = __builtin_amdgcn_mfma_f32_16x16x32_bf16(aq[0][kk], bk8, s[0], 0, 0, 0);
            s[1] = __builtin_amdgcn_mfma_f32_16x16x32_bf16(aq[1][kk], bk8, s[1], 0, 0, 0);
        }
        const int jg = j0 + w * 16 + lr;
        #pragma unroll
        for (int m = 0; m < 2; ++m)
            #pragma unroll
            for (int r = 0; r < 4; ++r) {
                const int ig = i0 + m * 16 + lg * 4 + r;
                psum[m][r] += (jg <= ig) ? __expf(s[m][r]) : 0.f;
            }
    }
    #pragma unroll
    for (int off = 1; off < 16; off <<= 1)
        #pragma unroll
        for (int m = 0; m < 2; ++m)
            #pragma unroll
            for (int r = 0; r < 4; ++r)
                psum[m][r] += __shfl_xor(psum[m][r], off);
    if (lr == 0) {
        #pragma unroll
        for (int m = 0; m < 2; ++m)
            #pragma unroll
            for (int r = 0; r < 4; ++r)
                red[w][m * 16 + lg * 4 + r] = psum[m][r];
    }
    __syncthreads();
    if (tid < 32)
        lpart[(size_t)(i0 + tid) * TL + t] = red[0][tid] + red[1][tid] + red[2][tid] + red[3][tid];
}

// ---------------------------------------------------------------------------
// k_lred: linv[i] = 1 / sum_t lpart[i][t]
// ---------------------------------------------------------------------------
__global__ __launch_bounds__(256) void k_lred(const float* __restrict__ lpart,
                                              float* __restrict__ linv)
{
    const int i = blockIdx.x;
    const int tid = threadIdx.x;
    float s = 0.f;
    for (int t = tid; t < TL; t += 256) s += lpart[(size_t)i * TL + t];
    #pragma unroll
    for (int off = 32; off >= 1; off >>= 1) s += __shfl_down(s, off);
    __shared__ float red[4];
    if ((tid & 63) == 0) red[tid >> 6] = s;
    __syncthreads();
    if (tid == 0) linv[i] = 1.f / (red[0] + red[1] + red[2] + red[3]);
}

// ---------------------------------------------------------------------------
// k_pv: per (i-tile 32, t): recompute S (cooperative, waves split j),
// P = mask ? exp(s) : 0 -> bf16 in swizzled LDS; PV = P @ X via MFMA
// (waves split h, 192 each; x loaded per-lane dwords, L2-hot);
// epilogue: out = acc * linv[i], single write.
// ---------------------------------------------------------------------------
__global__ __launch_bounds__(256, 2) void k_pv(
    const unsigned short* __restrict__ qg, const unsigned short* __restrict__ kg,
    const float* __restrict__ x, const float* __restrict__ linv,
    float* __restrict__ out)
{
    __shared__ unsigned short P[32 * 64];    // [i][j] bf16, 16B-chunk XOR swizzle
    const int tid = threadIdx.x, lane = tid & 63, w = tid >> 6;
    const int lr = lane & 15, lg = lane >> 4;
    const int bid = blockIdx.x;
    const int lid = (bid & 7) * (4608 / 8) + (bid >> 3);   // XCD-chunk swizzle
    const int it = lid % 12, t = lid / 12;
    const int i0 = it * 32;
    const int h0 = w * 192;

    bf16x8 aq[2][4];
    #pragma unroll
    for (int m = 0; m < 2; ++m) {
        const unsigned short* qp = qg + ((size_t)(i0 + m * 16 + lr) * TL + t) * DD + lg * 8;
        #pragma unroll
        for (int kk = 0; kk < 4; ++kk) aq[m][kk] = *(const bf16x8*)(qp + kk * 32);
    }
    float lv[2][4];
    #pragma unroll
    for (int m = 0; m < 2; ++m)
        #pragma unroll
        for (int r = 0; r < 4; ++r) lv[m][r] = linv[i0 + m * 16 + lg * 4 + r];

    f32x4 acc[2][12];
    #pragma unroll
    for (int m = 0; m < 2; ++m)
        #pragma unroll
        for (int n = 0; n < 12; ++n) acc[m][n] = (f32x4){0.f, 0.f, 0.f, 0.f};

    const int jmax = i0 + 32;
    const int nch = (jmax + 63) >> 6;
    for (int c = 0; c < nch; ++c) {
        const int j0 = c * 64;
        __syncthreads();   // protect P from previous iteration's readers
        // ---- phase A: S for j-cols w*16..+16 ----
        f32x4 s[2] = { (f32x4){0,0,0,0}, (f32x4){0,0,0,0} };
        const unsigned short* kp = kg + ((size_t)(j0 + w * 16 + lr) * TL + t) * DD + lg * 8;
        #pragma unroll
        for (int kk = 0; kk < 4; ++kk) {
            const bf16x8 bk8 = *(const bf16x8*)(kp + kk * 32);
            s[0] = __builtin_amdgcn_mfma_f32_16x16x32_bf16(aq[0][kk], bk8, s[0], 0, 0, 0);
            s[1] = __builtin_amdgcn_mfma_f32_16x16x32_bf16(aq[1][kk], bk8, s[1], 0, 0, 0);
        }
        const int jg = j0 + w * 16 + lr;
        const int jl = w * 16 + lr;
        #pragma unroll
        for (int m = 0; m < 2; ++m)
            #pragma unroll
            for (int r = 0; r < 4; ++r) {
                const int il = m * 16 + lg * 4 + r;
                const float wv = (jg <= i0 + il) ? __expf(s[m][r]) : 0.f;
                P[il * 64 + (((jl >> 3) ^ (il & 7)) * 8) + (jl & 7)] = f2b(wv);
            }
        __syncthreads();
        // ---- phase B: PV over this 64-j chunk ----
        #pragma unroll
        for (int kk2 = 0; kk2 < 2; ++kk2) {
            bf16x8 pa[2];
            #pragma unroll
            for (int m = 0; m < 2; ++m) {
                const int il = m * 16 + lr;
                const int ch = kk2 * 4 + lg;
                pa[m] = *(const bf16x8*)&P[il * 64 + ((ch ^ (il & 7)) * 8)];
            }
            const float* rowp[8];
            #pragma unroll
            for (int jj = 0; jj < 8; ++jj)
                rowp[jj] = x + ((size_t)(j0 + kk2 * 32 + lg * 8 + jj) * TL + t) * HD + h0 + lr;
            #pragma unroll
            for (int n = 0; n < 12; ++n) {
                bf16x8 bx;
                #pragma unroll
                for (int jj = 0; jj < 8; ++jj) bx[jj] = (short)f2b(rowp[jj][n * 16]);
                acc[0][n] = __builtin_amdgcn_mfma_f32_16x16x32_bf16(pa[0], bx, acc[0][n], 0, 0, 0);
                acc[1][n] = __builtin_amdgcn_mfma_f32_16x16x32_bf16(pa[1], bx, acc[1][n], 0, 0, 0);
            }
        }
    }
    // ---- epilogue: normalize + single write ----
    #pragma unroll
    for (int m = 0; m < 2; ++m)
        #pragma unroll
        for (int r = 0; r < 4; ++r) {
            float* op = out + ((size_t)(i0 + m * 16 + lg * 4 + r) * TL + t) * HD + h0 + lr;
            const float sc = lv[m][r];
            #pragma unroll
            for (int n = 0; n < 12; ++n) op[n * 16] = acc[m][n][r] * sc;
        }
}

// ---------------------------------------------------------------------------
// k_row0: out[0] = x[0] passthrough
// ---------------------------------------------------------------------------
__global__ __launch_bounds__(256) void k_row0(const float* __restrict__ x,
                                              float* __restrict__ out)
{
    const int idx = blockIdx.x * 256 + threadIdx.x;   // 73728 float4
    ((float4*)out)[idx] = ((const float4*)x)[idx];
}

extern "C" void kernel_launch(void* const* d_in, const int* in_sizes, int n_in,
                              void* d_out, int out_size, void* d_ws, size_t ws_size,
                              hipStream_t stream)
{
    const float* x  = (const float*)d_in[0];
    const float* Wq = (const float*)d_in[1];
    const float* bq = (const float*)d_in[2];
    const float* Wk = (const float*)d_in[3];
    const float* bk = (const float*)d_in[4];
    float* out = (float*)d_out;

    unsigned short* Wt = (unsigned short*)d_ws;                 // 256*768
    unsigned short* qb = Wt + (size_t)256 * HD;                 // NT*TL*DD bf16
    unsigned short* kb = qb + (size_t)NT * TL * DD;             // NT*TL*DD bf16
    float* lpart = (float*)(kb + (size_t)NT * TL * DD);         // NT*TL f32
    float* linv  = lpart + (size_t)NT * TL;                     // NT f32

    kw_prep<<<dim3(768), 256, 0, stream>>>(Wq, Wk, Wt);
    k_proj<<<dim3(NT * TL / 64), 256, 0, stream>>>(x, Wt, bq, bk, qb, kb);
    k_stats<<<dim3(4608), 256, 0, stream>>>(qb, kb, lpart);
    k_lred<<<dim3(NT), 256, 0, stream>>>(lpart, linv);
    k_pv<<<dim3(4608), 256, 0, stream>>>(qb, kb, x, linv, out);
    k_row0<<<dim3(TL * HD / 4 / 256), 256, 0, stream>>>(x, out);
}

// Round 3
// 807.308 us; speedup vs baseline: 3.1813x; 1.0618x over previous
//
#include <hip/hip_runtime.h>
#include <hip/hip_bf16.h>
#include <math.h>

#define NT 384   // turns
#define TL 384   // per-turn seq len
#define HD 768   // hidden
#define DD 128   // qk proj dim

typedef __attribute__((ext_vector_type(8))) short bf16x8;
typedef __attribute__((ext_vector_type(8))) unsigned short u16x8;
typedef __attribute__((ext_vector_type(4))) float f32x4;

__device__ __forceinline__ unsigned short f2b(float f) {
    union { float f; unsigned int u; } v; v.f = f;
    unsigned int r = v.u + 0x7FFFu + ((v.u >> 16) & 1u);   // RNE
    return (unsigned short)(r >> 16);
}

// ---------------------------------------------------------------------------
// kw_prep: Wt[n][k] = bf16(n<128 ? Wq[k][n] : Wk[k][n-128]); [256][768]
// ---------------------------------------------------------------------------
__global__ __launch_bounds__(256) void kw_prep(
    const float* __restrict__ Wq, const float* __restrict__ Wk,
    unsigned short* __restrict__ Wt)
{
    const int idx = blockIdx.x * 256 + threadIdx.x;     // 0 .. 196607
    const int k = idx >> 8, n = idx & 255;
    const float v = (n < DD) ? Wq[(size_t)k * DD + n] : Wk[(size_t)k * DD + (n - DD)];
    Wt[(size_t)n * HD + k] = f2b(v);
}

// ---------------------------------------------------------------------------
// k_proj: MFMA GEMM  C[147456][256] = x[147456][768] @ (Wq|Wk)[768][256]
// ---------------------------------------------------------------------------
__global__ __launch_bounds__(256, 2) void k_proj(
    const float* __restrict__ x, const unsigned short* __restrict__ Wt,
    const float* __restrict__ bq, const float* __restrict__ bk,
    unsigned short* __restrict__ qg, unsigned short* __restrict__ kg)
{
    __shared__ unsigned short As[64 * 64];   // [m][k] bf16, 16B-chunk XOR swizzle
    const int tid = threadIdx.x;
    const int lane = tid & 63;
    const int w = tid >> 6;
    const int row0 = blockIdx.x * 64;
    const int n0w = w * 64;
    const int lr = lane & 15;
    const int lg = lane >> 4;

    f32x4 acc[4][4];
    #pragma unroll
    for (int m = 0; m < 4; ++m)
        #pragma unroll
        for (int n = 0; n < 4; ++n) acc[m][n] = (f32x4){0.f, 0.f, 0.f, 0.f};

    const int sm = tid >> 2;           // staging row 0..63
    const int sc0 = (tid & 3) * 2;     // staging 16B-chunk pair

    for (int k0 = 0; k0 < HD; k0 += 64) {
        __syncthreads();
        {   // stage A tile [64 m][64 k] as bf16, swizzled
            const float* xp = x + (size_t)(row0 + sm) * HD + k0 + (tid & 3) * 16;
            u16x8 v0, v1;
            #pragma unroll
            for (int u4 = 0; u4 < 2; ++u4) {
                float4 f = *(const float4*)(xp + u4 * 4);
                v0[u4*4+0] = f2b(f.x); v0[u4*4+1] = f2b(f.y);
                v0[u4*4+2] = f2b(f.z); v0[u4*4+3] = f2b(f.w);
            }
            #pragma unroll
            for (int u4 = 0; u4 < 2; ++u4) {
                float4 f = *(const float4*)(xp + 8 + u4 * 4);
                v1[u4*4+0] = f2b(f.x); v1[u4*4+1] = f2b(f.y);
                v1[u4*4+2] = f2b(f.z); v1[u4*4+3] = f2b(f.w);
            }
            *(u16x8*)&As[sm * 64 + ((sc0     ^ (sm & 7)) * 8)] = v0;
            *(u16x8*)&As[sm * 64 + (((sc0+1) ^ (sm & 7)) * 8)] = v1;
        }
        __syncthreads();
        #pragma unroll
        for (int kk = 0; kk < 2; ++kk) {
            bf16x8 a[4], b[4];
            #pragma unroll
            for (int m = 0; m < 4; ++m) {
                const int mi = m * 16 + lr;
                const int phys = (lg + kk * 4) ^ (mi & 7);
                a[m] = *(const bf16x8*)&As[mi * 64 + phys * 8];
            }
            #pragma unroll
            for (int n = 0; n < 4; ++n) {
                const int ncol = n0w + n * 16 + lr;
                b[n] = *(const bf16x8*)(Wt + (size_t)ncol * HD + k0 + kk * 32 + lg * 8);
            }
            #pragma unroll
            for (int m = 0; m < 4; ++m)
                #pragma unroll
                for (int n = 0; n < 4; ++n)
                    acc[m][n] = __builtin_amdgcn_mfma_f32_16x16x32_bf16(a[m], b[n], acc[m][n], 0, 0, 0);
        }
    }
    const float scale = 0.08838834764831845f;   // 1/sqrt(128), folded into q
    #pragma unroll
    for (int n = 0; n < 4; ++n) {
        const int ncol = n0w + n * 16 + lr;
        const bool isq = ncol < DD;
        const int d = isq ? ncol : ncol - DD;
        const float bias = isq ? bq[d] : bk[d];
        unsigned short* dst = isq ? qg : kg;
        #pragma unroll
        for (int m = 0; m < 4; ++m)
            #pragma unroll
            for (int r = 0; r < 4; ++r) {
                const int row = row0 + m * 16 + lg * 4 + r;
                float v = acc[m][n][r] + bias;
                if (isq) v *= scale;
                dst[(size_t)row * DD + d] = f2b(v);
            }
    }
}

// ---------------------------------------------------------------------------
// k_xt: xt[t][h][j] = bf16(x[j][t][h]).  Register-blocked 8x8 transpose,
// no LDS. Reads coalesced along h; writes 128B-contiguous along j.
// grid: (NT/64, 3*TL); thread owns 8 j x 8 h.
// ---------------------------------------------------------------------------
__global__ __launch_bounds__(256, 4) void k_xt(
    const float* __restrict__ x, unsigned short* __restrict__ xt)
{
    const int tid = threadIdx.x;
    const int hb = blockIdx.y % 3;         // h-tile of 256
    const int t  = blockIdx.y / 3;
    const int j0 = blockIdx.x * 64 + (tid >> 5) * 8;
    const int h0 = hb * 256 + (tid & 31) * 8;

    float v[8][8];
    #pragma unroll
    for (int r = 0; r < 8; ++r) {
        const float4 a = *(const float4*)&x[((size_t)(j0 + r) * TL + t) * HD + h0];
        const float4 b = *(const float4*)&x[((size_t)(j0 + r) * TL + t) * HD + h0 + 4];
        v[r][0] = a.x; v[r][1] = a.y; v[r][2] = a.z; v[r][3] = a.w;
        v[r][4] = b.x; v[r][5] = b.y; v[r][6] = b.z; v[r][7] = b.w;
    }
    #pragma unroll
    for (int e = 0; e < 8; ++e) {
        u16x8 w;
        #pragma unroll
        for (int r = 0; r < 8; ++r) w[r] = f2b(v[r][e]);
        *(u16x8*)&xt[((size_t)t * HD + h0 + e) * NT + j0] = w;
    }
}

// ---------------------------------------------------------------------------
// k_stats: per (i-tile 32, t): S = QK^T (MFMA), w = mask ? exp(s) : 0,
// lpart[i][t] = sum_j w. Waves split j (16 cols each) per 64-chunk.
// ---------------------------------------------------------------------------
__global__ __launch_bounds__(256, 4) void k_stats(
    const unsigned short* __restrict__ qg, const unsigned short* __restrict__ kg,
    float* __restrict__ lpart)
{
    __shared__ float red[4][32];
    const int tid = threadIdx.x, lane = tid & 63, w = tid >> 6;
    const int lr = lane & 15, lg = lane >> 4;
    const int bid = blockIdx.x;
    const int lid = (bid & 7) * (4608 / 8) + (bid >> 3);   // XCD-chunk swizzle
    const int it = lid % 12, t = lid / 12;
    const int i0 = it * 32;

    bf16x8 aq[2][4];
    #pragma unroll
    for (int m = 0; m < 2; ++m) {
        const unsigned short* qp = qg + ((size_t)(i0 + m * 16 + lr) * TL + t) * DD + lg * 8;
        #pragma unroll
        for (int kk = 0; kk < 4; ++kk) aq[m][kk] = *(const bf16x8*)(qp + kk * 32);
    }
    float psum[2][4];
    #pragma unroll
    for (int m = 0; m < 2; ++m)
        #pragma unroll
        for (int r = 0; r < 4; ++r) psum[m][r] = 0.f;

    const int jmax = i0 + 32;
    const int nch = (jmax + 63) >> 6;
    for (int c = 0; c < nch; ++c) {
        const int j0 = c * 64;
        f32x4 s[2] = { (f32x4){0,0,0,0}, (f32x4){0,0,0,0} };
        const unsigned short* kp = kg + ((size_t)(j0 + w * 16 + lr) * TL + t) * DD + lg * 8;
        #pragma unroll
        for (int kk = 0; kk < 4; ++kk) {
            const bf16x8 bk8 = *(const bf16x8*)(kp + kk * 32);
            s[0] = __builtin_amdgcn_mfma_f32_16x16x32_bf16(aq[0][kk], bk8, s[0], 0, 0, 0);
            s[1] = __builtin_amdgcn_mfma_f32_16x16x32_bf16(aq[1][kk], bk8, s[1], 0, 0, 0);
        }
        const int jg = j0 + w * 16 + lr;
        #pragma unroll
        for (int m = 0; m < 2; ++m)
            #pragma unroll
            for (int r = 0; r < 4; ++r) {
                const int ig = i0 + m * 16 + lg * 4 + r;
                psum[m][r] += (jg <= ig) ? __expf(s[m][r]) : 0.f;
            }
    }
    #pragma unroll
    for (int off = 1; off < 16; off <<= 1)
        #pragma unroll
        for (int m = 0; m < 2; ++m)
            #pragma unroll
            for (int r = 0; r < 4; ++r)
                psum[m][r] += __shfl_xor(psum[m][r], off);
    if (lr == 0) {
        #pragma unroll
        for (int m = 0; m < 2; ++m)
            #pragma unroll
            for (int r = 0; r < 4; ++r)
                red[w][m * 16 + lg * 4 + r] = psum[m][r];
    }
    __syncthreads();
    if (tid < 32)
        lpart[(size_t)(i0 + tid) * TL + t] = red[0][tid] + red[1][tid] + red[2][tid] + red[3][tid];
}

// ---------------------------------------------------------------------------
// k_lred: linv[i] = 1 / sum_t lpart[i][t]
// ---------------------------------------------------------------------------
__global__ __launch_bounds__(256) void k_lred(const float* __restrict__ lpart,
                                              float* __restrict__ linv)
{
    const int i = blockIdx.x;
    const int tid = threadIdx.x;
    float s = 0.f;
    for (int t = tid; t < TL; t += 256) s += lpart[(size_t)i * TL + t];
    #pragma unroll
    for (int off = 32; off >= 1; off >>= 1) s += __shfl_down(s, off);
    __shared__ float red[4];
    if ((tid & 63) == 0) red[tid >> 6] = s;
    __syncthreads();
    if (tid == 0) linv[i] = 1.f / (red[0] + red[1] + red[2] + red[3]);
}

// ---------------------------------------------------------------------------
// k_pv_xt: per (i-tile 32, t): recompute S (waves split j), P -> LDS bf16;
// PV via MFMA with B-frags as contiguous bf16x8 loads from xt[t][h][j].
// Epilogue: out = acc * linv[i], single write.
// ---------------------------------------------------------------------------
__global__ __launch_bounds__(256, 2) void k_pv_xt(
    const unsigned short* __restrict__ qg, const unsigned short* __restrict__ kg,
    const unsigned short* __restrict__ xt, const float* __restrict__ linv,
    float* __restrict__ out)
{
    __shared__ unsigned short P[32 * 64];    // [i][j] bf16, 16B-chunk XOR swizzle
    const int tid = threadIdx.x, lane = tid & 63, w = tid >> 6;
    const int lr = lane & 15, lg = lane >> 4;
    const int bid = blockIdx.x;
    const int lid = (bid & 7) * (4608 / 8) + (bid >> 3);   // XCD-chunk swizzle
    const int it = lid % 12, t = lid / 12;
    const int i0 = it * 32;
    const int h0 = w * 192;

    bf16x8 aq[2][4];
    #pragma unroll
    for (int m = 0; m < 2; ++m) {
        const unsigned short* qp = qg + ((size_t)(i0 + m * 16 + lr) * TL + t) * DD + lg * 8;
        #pragma unroll
        for (int kk = 0; kk < 4; ++kk) aq[m][kk] = *(const bf16x8*)(qp + kk * 32);
    }

    f32x4 acc[2][12];
    #pragma unroll
    for (int m = 0; m < 2; ++m)
        #pragma unroll
        for (int n = 0; n < 12; ++n) acc[m][n] = (f32x4){0.f, 0.f, 0.f, 0.f};

    const int jmax = i0 + 32;
    const int nch = (jmax + 63) >> 6;
    for (int c = 0; c < nch; ++c) {
        const int j0 = c * 64;
        __syncthreads();   // protect P from previous iteration's readers
        // ---- phase A: S for j-cols w*16..+16 ----
        f32x4 s[2] = { (f32x4){0,0,0,0}, (f32x4){0,0,0,0} };
        const unsigned short* kp = kg + ((size_t)(j0 + w * 16 + lr) * TL + t) * DD + lg * 8;
        #pragma unroll
        for (int kk = 0; kk < 4; ++kk) {
            const bf16x8 bk8 = *(const bf16x8*)(kp + kk * 32);
            s[0] = __builtin_amdgcn_mfma_f32_16x16x32_bf16(aq[0][kk], bk8, s[0], 0, 0, 0);
            s[1] = __builtin_amdgcn_mfma_f32_16x16x32_bf16(aq[1][kk], bk8, s[1], 0, 0, 0);
        }
        const int jg = j0 + w * 16 + lr;
        const int jl = w * 16 + lr;
        #pragma unroll
        for (int m = 0; m < 2; ++m)
            #pragma unroll
            for (int r = 0; r < 4; ++r) {
                const int il = m * 16 + lg * 4 + r;
                const float wv = (jg <= i0 + il) ? __expf(s[m][r]) : 0.f;
                P[il * 64 + (((jl >> 3) ^ (il & 7)) * 8) + (jl & 7)] = f2b(wv);
            }
        __syncthreads();
        // ---- phase B: PV over this 64-j chunk; B-frags contiguous from xt ----
        #pragma unroll
        for (int kk2 = 0; kk2 < 2; ++kk2) {
            bf16x8 pa[2];
            #pragma unroll
            for (int m = 0; m < 2; ++m) {
                const int il = m * 16 + lr;
                const int ch = kk2 * 4 + lg;
                pa[m] = *(const bf16x8*)&P[il * 64 + ((ch ^ (il & 7)) * 8)];
            }
            const unsigned short* xp = xt + ((size_t)t * HD + h0 + lr) * NT + j0 + kk2 * 32 + lg * 8;
            #pragma unroll
            for (int n = 0; n < 12; ++n) {
                const bf16x8 bx = *(const bf16x8*)(xp + (size_t)n * 16 * NT);
                acc[0][n] = __builtin_amdgcn_mfma_f32_16x16x32_bf16(pa[0], bx, acc[0][n], 0, 0, 0);
                acc[1][n] = __builtin_amdgcn_mfma_f32_16x16x32_bf16(pa[1], bx, acc[1][n], 0, 0, 0);
            }
        }
    }
    // ---- epilogue: normalize + single write ----
    #pragma unroll
    for (int m = 0; m < 2; ++m)
        #pragma unroll
        for (int r = 0; r < 4; ++r) {
            const float sc = linv[i0 + m * 16 + lg * 4 + r];
            float* op = out + ((size_t)(i0 + m * 16 + lg * 4 + r) * TL + t) * HD + h0 + lr;
            #pragma unroll
            for (int n = 0; n < 12; ++n) op[n * 16] = acc[m][n][r] * sc;
        }
}

// ---------------------------------------------------------------------------
// k_pv_old: fallback (round-2 proven) when ws_size can't hold xt.
// ---------------------------------------------------------------------------
__global__ __launch_bounds__(256, 2) void k_pv_old(
    const unsigned short* __restrict__ qg, const unsigned short* __restrict__ kg,
    const float* __restrict__ x, const float* __restrict__ linv,
    float* __restrict__ out)
{
    __shared__ unsigned short P[32 * 64];
    const int tid = threadIdx.x, lane = tid & 63, w = tid >> 6;
    const int lr = lane & 15, lg = lane >> 4;
    const int bid = blockIdx.x;
    const int lid = (bid & 7) * (4608 / 8) + (bid >> 3);
    const int it = lid % 12, t = lid / 12;
    const int i0 = it * 32;
    const int h0 = w * 192;

    bf16x8 aq[2][4];
    #pragma unroll
    for (int m = 0; m < 2; ++m) {
        const unsigned short* qp = qg + ((size_t)(i0 + m * 16 + lr) * TL + t) * DD + lg * 8;
        #pragma unroll
        for (int kk = 0; kk < 4; ++kk) aq[m][kk] = *(const bf16x8*)(qp + kk * 32);
    }
    float lv[2][4];
    #pragma unroll
    for (int m = 0; m < 2; ++m)
        #pragma unroll
        for (int r = 0; r < 4; ++r) lv[m][r] = linv[i0 + m * 16 + lg * 4 + r];

    f32x4 acc[2][12];
    #pragma unroll
    for (int m = 0; m < 2; ++m)
        #pragma unroll
        for (int n = 0; n < 12; ++n) acc[m][n] = (f32x4){0.f, 0.f, 0.f, 0.f};

    const int jmax = i0 + 32;
    const int nch = (jmax + 63) >> 6;
    for (int c = 0; c < nch; ++c) {
        const int j0 = c * 64;
        __syncthreads();
        f32x4 s[2] = { (f32x4){0,0,0,0}, (f32x4){0,0,0,0} };
        const unsigned short* kp = kg + ((size_t)(j0 + w * 16 + lr) * TL + t) * DD + lg * 8;
        #pragma unroll
        for (int kk = 0; kk < 4; ++kk) {
            const bf16x8 bk8 = *(const bf16x8*)(kp + kk * 32);
            s[0] = __builtin_amdgcn_mfma_f32_16x16x32_bf16(aq[0][kk], bk8, s[0], 0, 0, 0);
            s[1] = __builtin_amdgcn_mfma_f32_16x16x32_bf16(aq[1][kk], bk8, s[1], 0, 0, 0);
        }
        const int jg = j0 + w * 16 + lr;
        const int jl = w * 16 + lr;
        #pragma unroll
        for (int m = 0; m < 2; ++m)
            #pragma unroll
            for (int r = 0; r < 4; ++r) {
                const int il = m * 16 + lg * 4 + r;
                const float wv = (jg <= i0 + il) ? __expf(s[m][r]) : 0.f;
                P[il * 64 + (((jl >> 3) ^ (il & 7)) * 8) + (jl & 7)] = f2b(wv);
            }
        __syncthreads();
        #pragma unroll
        for (int kk2 = 0; kk2 < 2; ++kk2) {
            bf16x8 pa[2];
            #pragma unroll
            for (int m = 0; m < 2; ++m) {
                const int il = m * 16 + lr;
                const int ch = kk2 * 4 + lg;
                pa[m] = *(const bf16x8*)&P[il * 64 + ((ch ^ (il & 7)) * 8)];
            }
            const float* rowp[8];
            #pragma unroll
            for (int jj = 0; jj < 8; ++jj)
                rowp[jj] = x + ((size_t)(j0 + kk2 * 32 + lg * 8 + jj) * TL + t) * HD + h0 + lr;
            #pragma unroll
            for (int n = 0; n < 12; ++n) {
                bf16x8 bx;
                #pragma unroll
                for (int jj = 0; jj < 8; ++jj) bx[jj] = (short)f2b(rowp[jj][n * 16]);
                acc[0][n] = __builtin_amdgcn_mfma_f32_16x16x32_bf16(pa[0], bx, acc[0][n], 0, 0, 0);
                acc[1][n] = __builtin_amdgcn_mfma_f32_16x16x32_bf16(pa[1], bx, acc[1][n], 0, 0, 0);
            }
        }
    }
    #pragma unroll
    for (int m = 0; m < 2; ++m)
        #pragma unroll
        for (int r = 0; r < 4; ++r) {
            float* op = out + ((size_t)(i0 + m * 16 + lg * 4 + r) * TL + t) * HD + h0 + lr;
            const float sc = lv[m][r];
            #pragma unroll
            for (int n = 0; n < 12; ++n) op[n * 16] = acc[m][n][r] * sc;
        }
}

// ---------------------------------------------------------------------------
// k_row0: out[0] = x[0] passthrough
// ---------------------------------------------------------------------------
__global__ __launch_bounds__(256) void k_row0(const float* __restrict__ x,
                                              float* __restrict__ out)
{
    const int idx = blockIdx.x * 256 + threadIdx.x;   // 73728 float4
    ((float4*)out)[idx] = ((const float4*)x)[idx];
}

extern "C" void kernel_launch(void* const* d_in, const int* in_sizes, int n_in,
                              void* d_out, int out_size, void* d_ws, size_t ws_size,
                              hipStream_t stream)
{
    const float* x  = (const float*)d_in[0];
    const float* Wq = (const float*)d_in[1];
    const float* bq = (const float*)d_in[2];
    const float* Wk = (const float*)d_in[3];
    const float* bk = (const float*)d_in[4];
    float* out = (float*)d_out;

    unsigned short* Wt = (unsigned short*)d_ws;                 // 256*768 bf16
    unsigned short* qb = Wt + (size_t)256 * HD;                 // NT*TL*DD bf16
    unsigned short* kb = qb + (size_t)NT * TL * DD;             // NT*TL*DD bf16
    float* lpart = (float*)(kb + (size_t)NT * TL * DD);         // NT*TL f32
    float* linv  = lpart + (size_t)NT * TL;                     // NT f32
    unsigned short* xt = (unsigned short*)(linv + NT);          // TL*HD*NT bf16

    const size_t need = (size_t)256 * HD * 2
                      + (size_t)NT * TL * DD * 2 * 2
                      + (size_t)NT * TL * 4 + (size_t)NT * 4
                      + (size_t)TL * HD * NT * 2;
    const bool use_xt = ws_size >= need;

    kw_prep<<<dim3(768), 256, 0, stream>>>(Wq, Wk, Wt);
    k_proj<<<dim3(NT * TL / 64), 256, 0, stream>>>(x, Wt, bq, bk, qb, kb);
    if (use_xt)
        k_xt<<<dim3(NT / 64, 3 * TL), 256, 0, stream>>>(x, xt);
    k_stats<<<dim3(4608), 256, 0, stream>>>(qb, kb, lpart);
    k_lred<<<dim3(NT), 256, 0, stream>>>(lpart, linv);
    if (use_xt)
        k_pv_xt<<<dim3(4608), 256, 0, stream>>>(qb, kb, xt, linv, out);
    else
        k_pv_old<<<dim3(4608), 256, 0, stream>>>(qb, kb, x, linv, out);
    k_row0<<<dim3(TL * HD / 4 / 256), 256, 0, stream>>>(x, out);
}